// Round 16
// baseline (1025.384 us; speedup 1.0000x reference)
//
#include <hip/hip_runtime.h>

#define E_CNT 32768
#define V_CNT 98304
#define D_ 128
#define VOCAB_ 2000
#define ITERS_ 6

typedef unsigned short u16;
typedef unsigned int u32;
typedef _Float16 f16;
typedef __attribute__((ext_vector_type(8))) _Float16 f16x8;
typedef __attribute__((ext_vector_type(4))) float f32x4;

__device__ __forceinline__ f32x4 MFh(f16x8 a, f16x8 b, f32x4 c) {
    return __builtin_amdgcn_mfma_f32_16x16x32_f16(a, b, c, 0, 0, 0);
}
__device__ __forceinline__ float sigmoid_f(float x) {
    return __builtin_amdgcn_rcpf(1.0f + __expf(-x));
}
__device__ __forceinline__ float tanh_f(float x) {
    float ax = fabsf(x);
    float t = fmaf(-2.0f, __builtin_amdgcn_rcpf(__expf(2.0f * ax) + 1.0f), 1.0f);
    return copysignf(t, x);
}
__device__ __forceinline__ u16 f16bits(f16 h) {
    union { f16 f; u16 u; } cv; cv.f = h; return cv.u;
}
__device__ __forceinline__ f16 bits2f16(u16 u) {
    union { f16 f; u16 u; } cv; cv.u = u; return cv.f;
}

__global__ void detect_mask_kernel(const unsigned int* __restrict__ m, int* __restrict__ flag) {
    int i = blockIdx.x * 256 + threadIdx.x;
    if (i < 4096 && m[i] > 1u) atomicOr(flag, 1);
}

// Pack weights into MFMA fragment order.
// WvF (fp16): [nt(32)][kk(16)][lane(64)][8]  j = nt*16+(l&15), k = kk*32+(l>>4)*8+r
// WeF (fp16): [p(3)][nt(32)][kk(8)][64][8]
// OwF (fp16, single term): [nt(125)][kk(4)][64][8]
__global__ void prep_kernel(
    const float* __restrict__ Wih_v2e, const float* __restrict__ Whh_v2e,
    const float* __restrict__ bih_v2e, const float* __restrict__ bhh_v2e,
    const float* __restrict__ Wih_e2v, const float* __restrict__ Whh_e2v,
    const float* __restrict__ bih_e2v, const float* __restrict__ bhh_e2v,
    const float* __restrict__ out_w,
    f16* __restrict__ WvF, f16* __restrict__ WeF, f16* __restrict__ OwF,
    float* __restrict__ bv, float* __restrict__ be)
{
    int idx = blockIdx.x * 256 + threadIdx.x;
    if (idx < 262144) {
        const int r = idx & 7, l = (idx >> 3) & 63, t = idx >> 9;
        const int kk = t & 15, nt = t >> 4;
        const int j = nt * 16 + (l & 15);
        const int k = kk * 32 + (l >> 4) * 8 + r;
        const float w = (k < 384) ? Wih_v2e[j * 384 + k] : Whh_v2e[j * 128 + (k - 384)];
        WvF[idx] = (f16)w;
        return;
    }
    idx -= 262144;
    if (idx < 393216) {
        const int r = idx & 7, l = (idx >> 3) & 63, t = idx >> 9;  // t < 768
        const int kk = t & 7, nt = (t >> 3) & 31, p = t >> 8;
        const int j = nt * 16 + (l & 15);
        const int k = kk * 32 + (l >> 4) * 8 + r;
        const float w = (k < 128) ? Wih_e2v[(p * 512 + j) * 128 + k]
                                  : Whh_e2v[(p * 512 + j) * 128 + (k - 128)];
        WeF[idx] = (f16)w;
        return;
    }
    idx -= 393216;
    if (idx < 256000) {
        const int r = idx & 7, l = (idx >> 3) & 63, t = idx >> 9;  // t < 500
        const int kk = t & 3, nt = t >> 2;
        const int j = nt * 16 + (l & 15);
        const int k = kk * 32 + (l >> 4) * 8 + r;
        OwF[idx] = (f16)out_w[j * 128 + k];
        return;
    }
    idx -= 256000;
    if (idx < 512) { bv[idx] = bih_v2e[idx] + bhh_v2e[idx]; return; }
    idx -= 512;
    if (idx < 1536) { be[idx] = bih_e2v[idx] + bhh_e2v[idx]; return; }
}

// Persistent iteration kernel: 512 thr / 8 waves / 64 edges / all 6 iterations.
// Fragment-order LDS. r16: THREE barriers/iter (was six) while keeping 2 blocks/CU:
//   HV 48 KB static (single buffer)
//   HE ping-pong: 16 KB static (buf A) + 16 KB DYNAMIC (buf B) -> runtime 80 KB/block
//     = exactly 2 blocks/CU; allocator sees only 64 KB static -> 128-VGPR budget (r8).
// Barrier structure per iter:
//   v2e GEMM (reads HV + HErd) ; cellE writes HEwr       [no WAR barrier - dbuf]
//   B1: HEwr ready
//   e2v GEMM(p=0,1,2) read HEwr + HV; cells HOLD h packed in regs, update cvG4
//   B2: all HV reads done
//   masked HV writes from held regs
//   B3: iter end
// s_setprio(1) around MFMA clusters (T5 - cross-block phase diversity now exists).
__global__ __launch_bounds__(512)
void fused_kernel(
    const int* __restrict__ x_v,
    const float* __restrict__ emb,
    const float* __restrict__ eiw, const float* __restrict__ eib,
    const f16* __restrict__ WvF, const f16* __restrict__ WeF,
    const float* __restrict__ bv, const float* __restrict__ be,
    const void* __restrict__ mask, const int* __restrict__ flagp,
    float4* __restrict__ cvG4,
    f16* __restrict__ hvOut)
{
    __shared__ f16 HV[24576];    // 48 KB, fragment order
    __shared__ f16 HEa[8192];    // 16 KB, buffer A
    extern __shared__ f16 HEb[]; // 16 KB, buffer B (dynamic: invisible to allocator)

    const int tid = threadIdx.x;
    const int c = tid >> 6, l = tid & 63;
    const int lr = l & 15, lk = l >> 4;
    const int e0 = blockIdx.x * 64;

    // ---- init h_v from embeddings (fp16x8 chunks into fragment slots)
    for (int i = tid; i < 64 * 48; i += 512) {
        const int row = i / 48, seg = i % 48;
        int id = x_v[(e0 + row) * 3 + (seg >> 4)];
        if (id < 0 || id > VOCAB_) id = VOCAB_;
        const float* s = emb + id * D_ + ((seg * 8) & 127);
        float4 a = *(const float4*)s, b = *(const float4*)(s + 4);
        f16x8 H;
        H[0] = (f16)a.x; H[1] = (f16)a.y; H[2] = (f16)a.z; H[3] = (f16)a.w;
        H[4] = (f16)b.x; H[5] = (f16)b.y; H[6] = (f16)b.z; H[7] = (f16)b.w;
        *(f16x8*)&HV[((row >> 4) * 12 + (seg >> 2)) * 512 + (seg & 3) * 128 + (row & 15) * 8] = H;
    }
    // ---- init h_e^{(0)} into buffer A (it=0 read buffer)
    for (int i = tid; i < 64 * 16; i += 512) {
        const int row = i / 16, seg = i % 16;
        f16x8 H;
        #pragma unroll
        for (int j = 0; j < 8; ++j) H[j] = (f16)(eiw[seg * 8 + j] + eib[seg * 8 + j]);
        *(f16x8*)&HEa[((row >> 4) * 4 + (seg >> 2)) * 512 + (seg & 3) * 128 + (row & 15) * 8] = H;
    }

    // ---- per-lane constants
    const int isByte = *flagp;
    unsigned mbits[3];
    #pragma unroll
    for (int p = 0; p < 3; ++p) {
        unsigned mb = 0;
        #pragma unroll
        for (int mt = 0; mt < 4; ++mt)
            #pragma unroll
            for (int r = 0; r < 4; ++r) {
                const int v = (e0 + mt * 16 + lk * 4 + r) * 3 + p;
                const bool m = isByte ? (((const unsigned char*)mask)[v] != 0)
                                      : (((const int*)mask)[v] != 0);
                mb |= (unsigned)m << (mt * 4 + r);
            }
        mbits[p] = mb;
    }
    const int d = c * 16 + lr;
    const int wBase = (c >> 1) * 512 + ((c & 1) * 2 + (lr >> 3)) * 128 + lk * 32 + (lr & 7);
    float ce[4][4];
    #pragma unroll
    for (int mt = 0; mt < 4; ++mt)
        #pragma unroll
        for (int r = 0; r < 4; ++r) ce[mt][r] = 0.0f;

    __syncthreads();

    const f16* HVl = HV + l * 8;
    const size_t cvBase = (size_t)blockIdx.x * 12 * 512 + tid;   // float4 units

    #pragma unroll 1
    for (int it = 0; it < ITERS_; ++it) {
        const f16* HErd = (it & 1) ? HEb : HEa;   // h_e^{(it)}
        f16*       HEwr = (it & 1) ? HEa : HEb;   // h_e^{(it+1)}
        const f16* HErdl = HErd + l * 8;

        // ======== vertex -> edge: GEMM reads HV + HErd ========
        {
            f32x4 acc[4][4];
            #pragma unroll
            for (int mt = 0; mt < 4; ++mt)
                #pragma unroll
                for (int g = 0; g < 4; ++g) acc[mt][g] = (f32x4)0.0f;

            __builtin_amdgcn_s_setprio(1);
            #pragma unroll 2
            for (int kk = 0; kk < 16; ++kk) {
                f16x8 Ah[4];
                if (kk < 12) {
                    #pragma unroll
                    for (int mt = 0; mt < 4; ++mt)
                        Ah[mt] = *(const f16x8*)(HVl + (mt * 12 + kk) * 512);
                } else {
                    #pragma unroll
                    for (int mt = 0; mt < 4; ++mt)
                        Ah[mt] = *(const f16x8*)(HErdl + (mt * 4 + (kk - 12)) * 512);
                }
                #pragma unroll
                for (int g = 0; g < 4; ++g) {
                    f16x8 B = *(const f16x8*)(WvF + (((g * 8 + c) * 16 + kk) * 64 + l) * 8);
                    #pragma unroll
                    for (int mt = 0; mt < 4; ++mt)
                        acc[mt][g] = MFh(Ah[mt], B, acc[mt][g]);
                }
            }
            __builtin_amdgcn_s_setprio(0);

            // cellE writes HEwr - double-buffered, no WAR barrier needed
            const float bvi = bv[d], bvf = bv[128 + d], bvg = bv[256 + d], bvo = bv[384 + d];
            #pragma unroll
            for (int mt = 0; mt < 4; ++mt)
                #pragma unroll
                for (int r = 0; r < 4; ++r) {
                    float gi = sigmoid_f(acc[mt][0][r] + bvi);
                    float gf = sigmoid_f(acc[mt][1][r] + bvf);
                    float gg = tanh_f(acc[mt][2][r] + bvg);
                    float go = sigmoid_f(acc[mt][3][r] + bvo);
                    float cn = gf * ce[mt][r] + gi * gg;
                    ce[mt][r] = cn;
                    HEwr[wBase + mt * 2048 + r * 8] = (f16)(go * tanh_f(cn));
                }
        }
        __syncthreads();   // B1: HEwr visible for e2v

        // ======== edge -> vertex: 3 p-GEMMs (pure reads), cells hold h in regs ======
        const f16* HEwrl = HEwr + l * 8;
        u32 hold[3][4][2];   // packed 2xf16 per reg: h for (p, mt, r-pair)
        #pragma unroll 1
        for (int p = 0; p < 3; ++p) {
            f32x4 acc[4][4];
            #pragma unroll
            for (int mt = 0; mt < 4; ++mt)
                #pragma unroll
                for (int g = 0; g < 4; ++g) acc[mt][g] = (f32x4)0.0f;

            __builtin_amdgcn_s_setprio(1);
            #pragma unroll 2
            for (int kk = 0; kk < 8; ++kk) {
                f16x8 Ah[4];
                if (kk < 4) {
                    #pragma unroll
                    for (int mt = 0; mt < 4; ++mt)
                        Ah[mt] = *(const f16x8*)(HEwrl + (mt * 4 + kk) * 512);
                } else {
                    #pragma unroll
                    for (int mt = 0; mt < 4; ++mt)
                        Ah[mt] = *(const f16x8*)(HVl + (mt * 12 + p * 4 + (kk - 4)) * 512);
                }
                #pragma unroll
                for (int g = 0; g < 4; ++g) {
                    f16x8 B = *(const f16x8*)(WeF + ((((p * 32) + (g * 8 + c)) * 8 + kk) * 64 + l) * 8);
                    #pragma unroll
                    for (int mt = 0; mt < 4; ++mt)
                        acc[mt][g] = MFh(Ah[mt], B, acc[mt][g]);
                }
            }
            __builtin_amdgcn_s_setprio(0);

            const float bei = be[p * 512 + d], bef = be[p * 512 + 128 + d];
            const float beg = be[p * 512 + 256 + d], beo = be[p * 512 + 384 + d];
            #pragma unroll
            for (int mt = 0; mt < 4; ++mt) {
                const size_t ci = cvBase + (p * 4 + mt) * 512;
                float cvv[4] = {0.0f, 0.0f, 0.0f, 0.0f};
                if (it > 0) {
                    float4 t = cvG4[ci];
                    cvv[0] = t.x; cvv[1] = t.y; cvv[2] = t.z; cvv[3] = t.w;
                }
                u16 hb[4];
                #pragma unroll
                for (int r = 0; r < 4; ++r) {
                    float gi = sigmoid_f(acc[mt][0][r] + bei);
                    float gf = sigmoid_f(acc[mt][1][r] + bef);
                    float gg = tanh_f(acc[mt][2][r] + beg);
                    float go = sigmoid_f(acc[mt][3][r] + beo);
                    float cn = gf * cvv[r] + gi * gg;
                    const bool m = (mbits[p] >> (mt * 4 + r)) & 1u;
                    if (m) cvv[r] = cn;
                    hb[r] = f16bits((f16)(go * tanh_f(cn)));
                }
                cvG4[ci] = make_float4(cvv[0], cvv[1], cvv[2], cvv[3]);
                hold[p][mt][0] = (u32)hb[0] | ((u32)hb[1] << 16);
                hold[p][mt][1] = (u32)hb[2] | ((u32)hb[3] << 16);
            }
        }
        __syncthreads();   // B2: all e2v HV reads complete

        // ---- masked HV writes from held registers
        #pragma unroll
        for (int p = 0; p < 3; ++p)
            #pragma unroll
            for (int mt = 0; mt < 4; ++mt)
                #pragma unroll
                for (int r = 0; r < 4; ++r) {
                    if ((mbits[p] >> (mt * 4 + r)) & 1u) {
                        u32 w = hold[p][mt][r >> 1];
                        u16 hb = (r & 1) ? (u16)(w >> 16) : (u16)(w & 0xFFFF);
                        HV[wBase + mt * 6144 + p * 2048 + r * 8] = bits2f16(hb);
                    }
                }
        __syncthreads();   // B3: iter end - HV ready for next v2e
    }

    // ---- write final h_v (fp16) for the projection kernel: [vertex][128] row-major
    for (int i = tid; i < 64 * 48; i += 512) {
        const int row = i / 48, seg = i % 48;
        *(f16x8*)&hvOut[(size_t)(e0 + row) * 384 + seg * 8] =
            *(const f16x8*)&HV[((row >> 4) * 12 + (seg >> 2)) * 512 + (seg & 3) * 128 + (row & 15) * 8];
    }
}

// logits = h_v @ out_w^T + out_b, swapped MFMA operands (A=out_w, B=h_v) -> each lane
// holds 4 consecutive vocab cols for one vertex -> float4 stores.
// Single fp16 W term. 768 blocks x 256 thr -> full 98304-vertex coverage.
// 48 KB LDS anchor -> 3 blocks/CU model -> VGPR budget ~170. W register dbuf.
__global__ __launch_bounds__(256) void proj_kernel(
    const f16* __restrict__ hv, const f16* __restrict__ WF,
    const float* __restrict__ out_b, float* __restrict__ out)
{
    __shared__ char occ_pad[49152];
    const int tid = threadIdx.x, l = tid & 63;
    occ_pad[tid] = (char)tid;
    __syncthreads();
    {
        int keep = (int)occ_pad[(tid + 1) & 255];
        asm volatile("" :: "v"(keep));   // occupancy anchor stays live
    }

    const int wid = blockIdx.x * 4 + (tid >> 6);   // 0..3071
    const int v0 = wid * 32;
    const int lr = l & 15, lk = l >> 4;

    f16x8 Bv[2][4];
    #pragma unroll
    for (int vt = 0; vt < 2; ++vt)
        #pragma unroll
        for (int kk = 0; kk < 4; ++kk)
            Bv[vt][kk] = *(const f16x8*)(hv + (v0 + vt * 16 + lr) * D_ + kk * 32 + lk * 8);

    f16x8 Wc[4];
    #pragma unroll
    for (int kk = 0; kk < 4; ++kk)
        Wc[kk] = *(const f16x8*)(WF + (kk * 64 + l) * 8);

    #pragma unroll 2
    for (int nt = 0; nt < 125; ++nt) {
        f16x8 Wn[4];
        if (nt < 124) {
            #pragma unroll
            for (int kk = 0; kk < 4; ++kk)
                Wn[kk] = *(const f16x8*)(WF + (((nt + 1) * 4 + kk) * 64 + l) * 8);
        }
        f32x4 a0 = (f32x4)0.0f, a1 = (f32x4)0.0f;
        #pragma unroll
        for (int kk = 0; kk < 4; ++kk) {
            a0 = MFh(Wc[kk], Bv[0][kk], a0);
            a1 = MFh(Wc[kk], Bv[1][kk], a1);
        }
        const int n0 = nt * 16 + lk * 4;
        const float4 bb = *(const float4*)&out_b[n0];
        {
            const size_t v = (size_t)(v0 + lr);
            float4 o = make_float4(a0[0] + bb.x, a0[1] + bb.y, a0[2] + bb.z, a0[3] + bb.w);
            *(float4*)&out[v * VOCAB_ + n0] = o;
        }
        {
            const size_t v = (size_t)(v0 + 16 + lr);
            float4 o = make_float4(a1[0] + bb.x, a1[1] + bb.y, a1[2] + bb.z, a1[3] + bb.w);
            *(float4*)&out[v * VOCAB_ + n0] = o;
        }
        #pragma unroll
        for (int q = 0; q < 4; ++q) Wc[q] = Wn[q];
    }
}

extern "C" void kernel_launch(void* const* d_in, const int* in_sizes, int n_in,
                              void* d_out, int out_size, void* d_ws, size_t ws_size,
                              hipStream_t stream)
{
    const int*   x_v     = (const int*)  d_in[0];
    const void*  mask    = d_in[1];
    const float* emb     = (const float*)d_in[2];
    const float* eiw     = (const float*)d_in[3];
    const float* eib     = (const float*)d_in[4];
    const float* Wih_v2e = (const float*)d_in[5];
    const float* Whh_v2e = (const float*)d_in[6];
    const float* bih_v2e = (const float*)d_in[7];
    const float* bhh_v2e = (const float*)d_in[8];
    const float* Wih_e2v = (const float*)d_in[9];
    const float* Whh_e2v = (const float*)d_in[10];
    const float* bih_e2v = (const float*)d_in[11];
    const float* bhh_e2v = (const float*)d_in[12];
    const float* out_w   = (const float*)d_in[13];
    const float* out_b   = (const float*)d_in[14];
    float* out = (float*)d_out;

    // d_ws carve (~77.3 MB)
    char* ws = (char*)d_ws;
    f16*    hv   = (f16*)(ws);                  // 25165824 B
    f16*    WvF  = (f16*)(ws + 25165824);       // 524288
    f16*    WeF  = (f16*)(ws + 25690112);       // 786432
    f16*    OwF  = (f16*)(ws + 26476544);       // 512000
    float*  bv   = (float*)(ws + 26988544);     // 2048
    float*  be   = (float*)(ws + 26990592);     // 6144
    int*    flag = (int*)(ws + 26996736);       // 4
    float4* cvG4 = (float4*)(ws + 27000832);    // 50331648  [blk][p][mt][tid] float4

    hipFuncSetAttribute(reinterpret_cast<const void*>(fused_kernel),
                        hipFuncAttributeMaxDynamicSharedMemorySize, 16384);

    hipMemsetAsync(flag, 0, 4, stream);
    detect_mask_kernel<<<16, 256, 0, stream>>>((const unsigned int*)mask, flag);
    prep_kernel<<<3568, 256, 0, stream>>>(Wih_v2e, Whh_v2e, bih_v2e, bhh_v2e,
                                          Wih_e2v, Whh_e2v, bih_e2v, bhh_e2v, out_w,
                                          WvF, WeF, OwF, bv, be);
    fused_kernel<<<E_CNT / 64, 512, 16384, stream>>>(x_v, emb, eiw, eib,
                                                     WvF, WeF, bv, be,
                                                     mask, flag, cvG4, hv);
    proj_kernel<<<V_CNT / 128, 256, 0, stream>>>(hv, OwF, out_b, out);
}

// Round 17
// 807.449 us; speedup vs baseline: 1.2699x; 1.2699x over previous
//
#include <hip/hip_runtime.h>

#define E_CNT 32768
#define V_CNT 98304
#define D_ 128
#define VOCAB_ 2000
#define ITERS_ 6

typedef unsigned short u16;
typedef _Float16 f16;
typedef __attribute__((ext_vector_type(8))) _Float16 f16x8;
typedef __attribute__((ext_vector_type(4))) float f32x4;

__device__ __forceinline__ f32x4 MFh(f16x8 a, f16x8 b, f32x4 c) {
    return __builtin_amdgcn_mfma_f32_16x16x32_f16(a, b, c, 0, 0, 0);
}
__device__ __forceinline__ float sigmoid_f(float x) {
    return __builtin_amdgcn_rcpf(1.0f + __expf(-x));
}
__device__ __forceinline__ float tanh_f(float x) {
    float ax = fabsf(x);
    float t = fmaf(-2.0f, __builtin_amdgcn_rcpf(__expf(2.0f * ax) + 1.0f), 1.0f);
    return copysignf(t, x);
}

__global__ void detect_mask_kernel(const unsigned int* __restrict__ m, int* __restrict__ flag) {
    int i = blockIdx.x * 256 + threadIdx.x;
    if (i < 4096 && m[i] > 1u) atomicOr(flag, 1);
}

// Pack weights into MFMA fragment order.
// WvF (fp16): [nt(32)][kk(16)][lane(64)][8]  j = nt*16+(l&15), k = kk*32+(l>>4)*8+r
// WeF (fp16): [p(3)][nt(32)][kk(8)][64][8]
// OwF (fp16, single term): [nt(125)][kk(4)][64][8]
__global__ void prep_kernel(
    const float* __restrict__ Wih_v2e, const float* __restrict__ Whh_v2e,
    const float* __restrict__ bih_v2e, const float* __restrict__ bhh_v2e,
    const float* __restrict__ Wih_e2v, const float* __restrict__ Whh_e2v,
    const float* __restrict__ bih_e2v, const float* __restrict__ bhh_e2v,
    const float* __restrict__ out_w,
    f16* __restrict__ WvF, f16* __restrict__ WeF, f16* __restrict__ OwF,
    float* __restrict__ bv, float* __restrict__ be)
{
    int idx = blockIdx.x * 256 + threadIdx.x;
    if (idx < 262144) {
        const int r = idx & 7, l = (idx >> 3) & 63, t = idx >> 9;
        const int kk = t & 15, nt = t >> 4;
        const int j = nt * 16 + (l & 15);
        const int k = kk * 32 + (l >> 4) * 8 + r;
        const float w = (k < 384) ? Wih_v2e[j * 384 + k] : Whh_v2e[j * 128 + (k - 384)];
        WvF[idx] = (f16)w;
        return;
    }
    idx -= 262144;
    if (idx < 393216) {
        const int r = idx & 7, l = (idx >> 3) & 63, t = idx >> 9;  // t < 768
        const int kk = t & 7, nt = (t >> 3) & 31, p = t >> 8;
        const int j = nt * 16 + (l & 15);
        const int k = kk * 32 + (l >> 4) * 8 + r;
        const float w = (k < 128) ? Wih_e2v[(p * 512 + j) * 128 + k]
                                  : Whh_e2v[(p * 512 + j) * 128 + (k - 128)];
        WeF[idx] = (f16)w;
        return;
    }
    idx -= 393216;
    if (idx < 256000) {
        const int r = idx & 7, l = (idx >> 3) & 63, t = idx >> 9;  // t < 500
        const int kk = t & 3, nt = t >> 2;
        const int j = nt * 16 + (l & 15);
        const int k = kk * 32 + (l >> 4) * 8 + r;
        OwF[idx] = (f16)out_w[j * 128 + k];
        return;
    }
    idx -= 256000;
    if (idx < 512) { bv[idx] = bih_v2e[idx] + bhh_v2e[idx]; return; }
    idx -= 512;
    if (idx < 1536) { be[idx] = bih_e2v[idx] + bhh_e2v[idx]; return; }
}

// Persistent iteration kernel: 1024 thr / 16 waves / 128 edges / all 6 iterations.
// r17: 256 blocks = EXACTLY 1/CU, 16 waves/CU = 4 waves/SIMD (r8-r16 ran one
// 512-thr block/CU = 2 waves/SIMD per OccupancyPercent ~23.5%; r6's 1024-thr showed
// ~44%). Same r15 inner structure (6 barriers/iter, no setprio, no held writes).
// Wave (c, wm) = (w&7, w>>3): gate-slice d = c*16+lr, edge-half wm (mtg = wm*4+mt).
// LDS 128 KB STATIC (fragment order; visible to allocator -> 1-block model ->
// honest 128-VGPR budget, r8 mechanism): HV[mtg(8)][kk(12)][64][8] 96 KB +
// HE[mtg(8)][kk(4)][64][8] 32 KB. Weight L2 traffic halves (256 vs 512 blocks).
// c_v in coalesced fragment layout (r15): cvG4[blk][p*8+mtg][tid&511] float4.
__global__ __launch_bounds__(1024)
void fused_kernel(
    const int* __restrict__ x_v,
    const float* __restrict__ emb,
    const float* __restrict__ eiw, const float* __restrict__ eib,
    const f16* __restrict__ WvF, const f16* __restrict__ WeF,
    const float* __restrict__ bv, const float* __restrict__ be,
    const void* __restrict__ mask, const int* __restrict__ flagp,
    float4* __restrict__ cvG4,
    f16* __restrict__ hvOut)
{
    __shared__ f16 HV[49152];   // 96 KB, fragment order [mtg*12+kk][lane][8]
    __shared__ f16 HE[16384];   // 32 KB, fragment order [mtg*4+kk][lane][8]

    const int tid = threadIdx.x;
    const int w = tid >> 6, l = tid & 63;
    const int c = w & 7, mtb = (w >> 3) * 4;     // wave's gate-slice, edge-half base
    const int lr = l & 15, lk = l >> 4;
    const int e0 = blockIdx.x * 128;

    // ---- init h_v from embeddings (fp16x8 chunks into fragment slots)
    for (int i = tid; i < 128 * 48; i += 1024) {
        const int row = i / 48, seg = i % 48;
        int id = x_v[(e0 + row) * 3 + (seg >> 4)];
        if (id < 0 || id > VOCAB_) id = VOCAB_;
        const float* s = emb + id * D_ + ((seg * 8) & 127);
        float4 a = *(const float4*)s, b = *(const float4*)(s + 4);
        f16x8 H;
        H[0] = (f16)a.x; H[1] = (f16)a.y; H[2] = (f16)a.z; H[3] = (f16)a.w;
        H[4] = (f16)b.x; H[5] = (f16)b.y; H[6] = (f16)b.z; H[7] = (f16)b.w;
        *(f16x8*)&HV[((row >> 4) * 12 + (seg >> 2)) * 512 + (seg & 3) * 128 + (row & 15) * 8] = H;
    }
    // ---- init h_e (same vector for every edge)
    for (int i = tid; i < 128 * 16; i += 1024) {
        const int row = i / 16, seg = i % 16;
        f16x8 H;
        #pragma unroll
        for (int j = 0; j < 8; ++j) H[j] = (f16)(eiw[seg * 8 + j] + eib[seg * 8 + j]);
        *(f16x8*)&HE[((row >> 4) * 4 + (seg >> 2)) * 512 + (seg & 3) * 128 + (row & 15) * 8] = H;
    }

    // ---- per-lane constants
    const int isByte = *flagp;
    unsigned mbits[3];
    #pragma unroll
    for (int p = 0; p < 3; ++p) {
        unsigned mb = 0;
        #pragma unroll
        for (int mt = 0; mt < 4; ++mt)
            #pragma unroll
            for (int r = 0; r < 4; ++r) {
                const int v = (e0 + (mtb + mt) * 16 + lk * 4 + r) * 3 + p;
                const bool m = isByte ? (((const unsigned char*)mask)[v] != 0)
                                      : (((const int*)mask)[v] != 0);
                mb |= (unsigned)m << (mt * 4 + r);
            }
        mbits[p] = mb;
    }
    const int d = c * 16 + lr;
    // fragment-coords of this thread's write column d (per-thread constants)
    const int wBase = (c >> 1) * 512 + ((c & 1) * 2 + (lr >> 3)) * 128 + lk * 32 + (lr & 7);
    float ce[4][4];
    #pragma unroll
    for (int mt = 0; mt < 4; ++mt)
        #pragma unroll
        for (int r = 0; r < 4; ++r) ce[mt][r] = 0.0f;

    __syncthreads();

    const f16* HVl = HV + l * 8;   // lane-linear bases: all reads are base + imm
    const f16* HEl = HE + l * 8;
    const size_t cvBase = (size_t)blockIdx.x * 12288 + (tid & 511);   // float4 units

    #pragma unroll 1
    for (int it = 0; it < ITERS_; ++it) {
        // ======== vertex -> edge ========
        {
            f32x4 acc[4][4];
            #pragma unroll
            for (int mt = 0; mt < 4; ++mt)
                #pragma unroll
                for (int g = 0; g < 4; ++g) acc[mt][g] = (f32x4)0.0f;

            #pragma unroll 2
            for (int kk = 0; kk < 16; ++kk) {
                f16x8 Ah[4];
                if (kk < 12) {
                    #pragma unroll
                    for (int mt = 0; mt < 4; ++mt)
                        Ah[mt] = *(const f16x8*)(HVl + ((mtb + mt) * 12 + kk) * 512);
                } else {
                    #pragma unroll
                    for (int mt = 0; mt < 4; ++mt)
                        Ah[mt] = *(const f16x8*)(HEl + ((mtb + mt) * 4 + (kk - 12)) * 512);
                }
                #pragma unroll
                for (int g = 0; g < 4; ++g) {
                    f16x8 B = *(const f16x8*)(WvF + (((g * 8 + c) * 16 + kk) * 64 + l) * 8);
                    #pragma unroll
                    for (int mt = 0; mt < 4; ++mt)
                        acc[mt][g] = MFh(Ah[mt], B, acc[mt][g]);
                }
            }
            __syncthreads();   // all HE reads done before HE writes
            const float bvi = bv[d], bvf = bv[128 + d], bvg = bv[256 + d], bvo = bv[384 + d];
            #pragma unroll
            for (int mt = 0; mt < 4; ++mt)
                #pragma unroll
                for (int r = 0; r < 4; ++r) {
                    float gi = sigmoid_f(acc[mt][0][r] + bvi);
                    float gf = sigmoid_f(acc[mt][1][r] + bvf);
                    float gg = tanh_f(acc[mt][2][r] + bvg);
                    float go = sigmoid_f(acc[mt][3][r] + bvo);
                    float cn = gf * ce[mt][r] + gi * gg;
                    ce[mt][r] = cn;
                    HE[wBase + (mtb + mt) * 2048 + r * 8] = (f16)(go * tanh_f(cn));
                }
            __syncthreads();   // HE complete before e2v reads
        }
        // ======== edge -> vertex (3 position-specific LSTMs) ========
        #pragma unroll 1
        for (int p = 0; p < 3; ++p) {
            f32x4 acc[4][4];
            #pragma unroll
            for (int mt = 0; mt < 4; ++mt)
                #pragma unroll
                for (int g = 0; g < 4; ++g) acc[mt][g] = (f32x4)0.0f;

            #pragma unroll 2
            for (int kk = 0; kk < 8; ++kk) {
                f16x8 Ah[4];
                if (kk < 4) {
                    #pragma unroll
                    for (int mt = 0; mt < 4; ++mt)
                        Ah[mt] = *(const f16x8*)(HEl + ((mtb + mt) * 4 + kk) * 512);
                } else {
                    #pragma unroll
                    for (int mt = 0; mt < 4; ++mt)
                        Ah[mt] = *(const f16x8*)(HVl + ((mtb + mt) * 12 + p * 4 + (kk - 4)) * 512);
                }
                #pragma unroll
                for (int g = 0; g < 4; ++g) {
                    f16x8 B = *(const f16x8*)(WeF + ((((p * 32) + (g * 8 + c)) * 8 + kk) * 64 + l) * 8);
                    #pragma unroll
                    for (int mt = 0; mt < 4; ++mt)
                        acc[mt][g] = MFh(Ah[mt], B, acc[mt][g]);
                }
            }
            __syncthreads();   // all HV[p]/HE reads done before HV[p] writes
            const float bei = be[p * 512 + d], bef = be[p * 512 + 128 + d];
            const float beg = be[p * 512 + 256 + d], beo = be[p * 512 + 384 + d];
            #pragma unroll
            for (int mt = 0; mt < 4; ++mt) {
                // ONE coalesced float4 load + store per (wave,p,mt)
                const size_t ci = cvBase + (size_t)(p * 8 + mtb + mt) * 512;
                float cvv[4] = {0.0f, 0.0f, 0.0f, 0.0f};
                if (it > 0) {
                    float4 t = cvG4[ci];
                    cvv[0] = t.x; cvv[1] = t.y; cvv[2] = t.z; cvv[3] = t.w;
                }
                #pragma unroll
                for (int r = 0; r < 4; ++r) {
                    if ((mbits[p] >> (mt * 4 + r)) & 1u) {
                        float gi = sigmoid_f(acc[mt][0][r] + bei);
                        float gf = sigmoid_f(acc[mt][1][r] + bef);
                        float gg = tanh_f(acc[mt][2][r] + beg);
                        float go = sigmoid_f(acc[mt][3][r] + beo);
                        float cn = gf * cvv[r] + gi * gg;
                        cvv[r] = cn;
                        HV[wBase + (mtb + mt) * 6144 + p * 2048 + r * 8] = (f16)(go * tanh_f(cn));
                    }
                }
                cvG4[ci] = make_float4(cvv[0], cvv[1], cvv[2], cvv[3]);
            }
            // no barrier between cell(p) and GEMM(p+1): cell writes HV col-tiles
            // 4p..4p+3, GEMM(p+1) reads col-tiles 4(p+1).. and HE - disjoint
        }
        __syncthreads();       // HV writes complete before next v2e (or copy-out)
    }

    // ---- write final h_v (fp16) for the projection kernel: [vertex][128] row-major
    for (int i = tid; i < 128 * 48; i += 1024) {
        const int row = i / 48, seg = i % 48;
        *(f16x8*)&hvOut[(size_t)(e0 + row) * 384 + seg * 8] =
            *(const f16x8*)&HV[((row >> 4) * 12 + (seg >> 2)) * 512 + (seg & 3) * 128 + (row & 15) * 8];
    }
}

// logits = h_v @ out_w^T + out_b, swapped MFMA operands (A=out_w, B=h_v) -> each lane
// holds 4 consecutive vocab cols for one vertex -> float4 stores.
// Single fp16 W term. 768 blocks x 256 thr -> full 98304-vertex coverage.
// 48 KB LDS anchor -> 3 blocks/CU model -> VGPR budget ~170. W register dbuf.
__global__ __launch_bounds__(256) void proj_kernel(
    const f16* __restrict__ hv, const f16* __restrict__ WF,
    const float* __restrict__ out_b, float* __restrict__ out)
{
    __shared__ char occ_pad[49152];
    const int tid = threadIdx.x, l = tid & 63;
    occ_pad[tid] = (char)tid;
    __syncthreads();
    {
        int keep = (int)occ_pad[(tid + 1) & 255];
        asm volatile("" :: "v"(keep));   // occupancy anchor stays live
    }

    const int wid = blockIdx.x * 4 + (tid >> 6);   // 0..3071
    const int v0 = wid * 32;
    const int lr = l & 15, lk = l >> 4;

    f16x8 Bv[2][4];
    #pragma unroll
    for (int vt = 0; vt < 2; ++vt)
        #pragma unroll
        for (int kk = 0; kk < 4; ++kk)
            Bv[vt][kk] = *(const f16x8*)(hv + (v0 + vt * 16 + lr) * D_ + kk * 32 + lk * 8);

    f16x8 Wc[4];
    #pragma unroll
    for (int kk = 0; kk < 4; ++kk)
        Wc[kk] = *(const f16x8*)(WF + (kk * 64 + l) * 8);

    #pragma unroll 2
    for (int nt = 0; nt < 125; ++nt) {
        f16x8 Wn[4];
        if (nt < 124) {
            #pragma unroll
            for (int kk = 0; kk < 4; ++kk)
                Wn[kk] = *(const f16x8*)(WF + (((nt + 1) * 4 + kk) * 64 + l) * 8);
        }
        f32x4 a0 = (f32x4)0.0f, a1 = (f32x4)0.0f;
        #pragma unroll
        for (int kk = 0; kk < 4; ++kk) {
            a0 = MFh(Wc[kk], Bv[0][kk], a0);
            a1 = MFh(Wc[kk], Bv[1][kk], a1);
        }
        const int n0 = nt * 16 + lk * 4;
        const float4 bb = *(const float4*)&out_b[n0];
        {
            const size_t v = (size_t)(v0 + lr);
            float4 o = make_float4(a0[0] + bb.x, a0[1] + bb.y, a0[2] + bb.z, a0[3] + bb.w);
            *(float4*)&out[v * VOCAB_ + n0] = o;
        }
        {
            const size_t v = (size_t)(v0 + 16 + lr);
            float4 o = make_float4(a1[0] + bb.x, a1[1] + bb.y, a1[2] + bb.z, a1[3] + bb.w);
            *(float4*)&out[v * VOCAB_ + n0] = o;
        }
        #pragma unroll
        for (int q = 0; q < 4; ++q) Wc[q] = Wn[q];
    }
}

extern "C" void kernel_launch(void* const* d_in, const int* in_sizes, int n_in,
                              void* d_out, int out_size, void* d_ws, size_t ws_size,
                              hipStream_t stream)
{
    const int*   x_v     = (const int*)  d_in[0];
    const void*  mask    = d_in[1];
    const float* emb     = (const float*)d_in[2];
    const float* eiw     = (const float*)d_in[3];
    const float* eib     = (const float*)d_in[4];
    const float* Wih_v2e = (const float*)d_in[5];
    const float* Whh_v2e = (const float*)d_in[6];
    const float* bih_v2e = (const float*)d_in[7];
    const float* bhh_v2e = (const float*)d_in[8];
    const float* Wih_e2v = (const float*)d_in[9];
    const float* Whh_e2v = (const float*)d_in[10];
    const float* bih_e2v = (const float*)d_in[11];
    const float* bhh_e2v = (const float*)d_in[12];
    const float* out_w   = (const float*)d_in[13];
    const float* out_b   = (const float*)d_in[14];
    float* out = (float*)d_out;

    // d_ws carve (~77.3 MB)
    char* ws = (char*)d_ws;
    f16*    hv   = (f16*)(ws);                  // 25165824 B
    f16*    WvF  = (f16*)(ws + 25165824);       // 524288
    f16*    WeF  = (f16*)(ws + 25690112);       // 786432
    f16*    OwF  = (f16*)(ws + 26476544);       // 512000
    float*  bv   = (float*)(ws + 26988544);     // 2048
    float*  be   = (float*)(ws + 26990592);     // 6144
    int*    flag = (int*)(ws + 26996736);       // 4
    float4* cvG4 = (float4*)(ws + 27000832);    // 50331648  [blk][p*8+mtg][tid&511] f4

    hipMemsetAsync(flag, 0, 4, stream);
    detect_mask_kernel<<<16, 256, 0, stream>>>((const unsigned int*)mask, flag);
    prep_kernel<<<3568, 256, 0, stream>>>(Wih_v2e, Whh_v2e, bih_v2e, bhh_v2e,
                                          Wih_e2v, Whh_e2v, bih_e2v, bhh_e2v, out_w,
                                          WvF, WeF, OwF, bv, be);
    fused_kernel<<<E_CNT / 128, 1024, 0, stream>>>(x_v, emb, eiw, eib,
                                                   WvF, WeF, bv, be,
                                                   mask, flag, cvG4, hv);
    proj_kernel<<<V_CNT / 128, 256, 0, stream>>>(hv, OwF, out_b, out);
}

// Round 18
// 803.387 us; speedup vs baseline: 1.2763x; 1.0051x over previous
//
#include <hip/hip_runtime.h>

#define E_CNT 32768
#define V_CNT 98304
#define D_ 128
#define VOCAB_ 2000
#define ITERS_ 6

typedef unsigned short u16;
typedef _Float16 f16;
typedef __attribute__((ext_vector_type(8))) _Float16 f16x8;
typedef __attribute__((ext_vector_type(4))) float f32x4;

__device__ __forceinline__ f32x4 MFh(f16x8 a, f16x8 b, f32x4 c) {
    return __builtin_amdgcn_mfma_f32_16x16x32_f16(a, b, c, 0, 0, 0);
}
__device__ __forceinline__ float sigmoid_f(float x) {
    return __builtin_amdgcn_rcpf(1.0f + __expf(-x));
}
// branch-free tanh: 2*sigmoid(2x) - 1 (saturates correctly at both ends via exp->inf/0)
__device__ __forceinline__ float tanh_f(float x) {
    return fmaf(2.0f, __builtin_amdgcn_rcpf(1.0f + __expf(-2.0f * x)), -1.0f);
}

__global__ void detect_mask_kernel(const unsigned int* __restrict__ m, int* __restrict__ flag) {
    int i = blockIdx.x * 256 + threadIdx.x;
    if (i < 4096 && m[i] > 1u) atomicOr(flag, 1);
}

// Pack weights into MFMA fragment order.
// WvF (fp16): [nt(32)][kk(16)][lane(64)][8]  j = nt*16+(l&15), k = kk*32+(l>>4)*8+r
// WeF (fp16): [p(3)][nt(32)][kk(8)][64][8]
// OwF (fp16, single term): [nt(125)][kk(4)][64][8]
__global__ void prep_kernel(
    const float* __restrict__ Wih_v2e, const float* __restrict__ Whh_v2e,
    const float* __restrict__ bih_v2e, const float* __restrict__ bhh_v2e,
    const float* __restrict__ Wih_e2v, const float* __restrict__ Whh_e2v,
    const float* __restrict__ bih_e2v, const float* __restrict__ bhh_e2v,
    const float* __restrict__ out_w,
    f16* __restrict__ WvF, f16* __restrict__ WeF, f16* __restrict__ OwF,
    float* __restrict__ bv, float* __restrict__ be)
{
    int idx = blockIdx.x * 256 + threadIdx.x;
    if (idx < 262144) {
        const int r = idx & 7, l = (idx >> 3) & 63, t = idx >> 9;
        const int kk = t & 15, nt = t >> 4;
        const int j = nt * 16 + (l & 15);
        const int k = kk * 32 + (l >> 4) * 8 + r;
        const float w = (k < 384) ? Wih_v2e[j * 384 + k] : Whh_v2e[j * 128 + (k - 384)];
        WvF[idx] = (f16)w;
        return;
    }
    idx -= 262144;
    if (idx < 393216) {
        const int r = idx & 7, l = (idx >> 3) & 63, t = idx >> 9;  // t < 768
        const int kk = t & 7, nt = (t >> 3) & 31, p = t >> 8;
        const int j = nt * 16 + (l & 15);
        const int k = kk * 32 + (l >> 4) * 8 + r;
        const float w = (k < 128) ? Wih_e2v[(p * 512 + j) * 128 + k]
                                  : Whh_e2v[(p * 512 + j) * 128 + (k - 128)];
        WeF[idx] = (f16)w;
        return;
    }
    idx -= 393216;
    if (idx < 256000) {
        const int r = idx & 7, l = (idx >> 3) & 63, t = idx >> 9;  // t < 500
        const int kk = t & 3, nt = t >> 2;
        const int j = nt * 16 + (l & 15);
        const int k = kk * 32 + (l >> 4) * 8 + r;
        OwF[idx] = (f16)out_w[j * 128 + k];
        return;
    }
    idx -= 256000;
    if (idx < 512) { bv[idx] = bih_v2e[idx] + bhh_v2e[idx]; return; }
    idx -= 512;
    if (idx < 1536) { be[idx] = bih_e2v[idx] + bhh_e2v[idx]; return; }
}

// Persistent iteration kernel: 512 thr / 8 waves / 64 edges / all 6 iterations.
// r18: COMPACT UNIFIED PHASE LOOP - one GEMM body + one cell body reused for all 4
// phases (v2e, e2v p=0..2) via wave-uniform scalar selects. Rationale: r15 vs r17
// showed fused time invariant (~525us) across 2x occupancy and spill/no-spill ->
// suspect instruction-footprint (unrolled 5-phase body >> I$); this shrinks the
// loop body ~10x. Also: bias pre-loaded into MFMA accumulators; branch-free tanh.
// Same r15 layout: fragment-order LDS 64 KB static (2-block model -> honest 128-VGPR
// budget), 6 barriers/iter, coalesced cvG4 state.
__global__ __launch_bounds__(512)
void fused_kernel(
    const int* __restrict__ x_v,
    const float* __restrict__ emb,
    const float* __restrict__ eiw, const float* __restrict__ eib,
    const f16* __restrict__ WvF, const f16* __restrict__ WeF,
    const float* __restrict__ bv, const float* __restrict__ be,
    const void* __restrict__ mask, const int* __restrict__ flagp,
    float4* __restrict__ cvG4,
    f16* __restrict__ hvOut)
{
    __shared__ f16 HV[24576];   // 48 KB, fragment order [mt*12+kk][lane][8]
    __shared__ f16 HE[8192];    // 16 KB, fragment order [mt*4+kk][lane][8]

    const int tid = threadIdx.x;
    const int c = tid >> 6, l = tid & 63;
    const int lr = l & 15, lk = l >> 4;
    const int e0 = blockIdx.x * 64;

    // ---- init h_v from embeddings (fp16x8 chunks into fragment slots)
    for (int i = tid; i < 64 * 48; i += 512) {
        const int row = i / 48, seg = i % 48;
        int id = x_v[(e0 + row) * 3 + (seg >> 4)];
        if (id < 0 || id > VOCAB_) id = VOCAB_;
        const float* s = emb + id * D_ + ((seg * 8) & 127);
        float4 a = *(const float4*)s, b = *(const float4*)(s + 4);
        f16x8 H;
        H[0] = (f16)a.x; H[1] = (f16)a.y; H[2] = (f16)a.z; H[3] = (f16)a.w;
        H[4] = (f16)b.x; H[5] = (f16)b.y; H[6] = (f16)b.z; H[7] = (f16)b.w;
        *(f16x8*)&HV[((row >> 4) * 12 + (seg >> 2)) * 512 + (seg & 3) * 128 + (row & 15) * 8] = H;
    }
    // ---- init h_e (same vector for every edge)
    for (int i = tid; i < 64 * 16; i += 512) {
        const int row = i / 16, seg = i % 16;
        f16x8 H;
        #pragma unroll
        for (int j = 0; j < 8; ++j) H[j] = (f16)(eiw[seg * 8 + j] + eib[seg * 8 + j]);
        *(f16x8*)&HE[((row >> 4) * 4 + (seg >> 2)) * 512 + (seg & 3) * 128 + (row & 15) * 8] = H;
    }

    // ---- per-lane constants (separate scalars - no runtime-indexed arrays, rule #20)
    const int isByte = *flagp;
    unsigned mbits0 = 0, mbits1 = 0, mbits2 = 0;
    #pragma unroll
    for (int p = 0; p < 3; ++p) {
        unsigned mb = 0;
        #pragma unroll
        for (int mt = 0; mt < 4; ++mt)
            #pragma unroll
            for (int r = 0; r < 4; ++r) {
                const int v = (e0 + mt * 16 + lk * 4 + r) * 3 + p;
                const bool m = isByte ? (((const unsigned char*)mask)[v] != 0)
                                      : (((const int*)mask)[v] != 0);
                mb |= (unsigned)m << (mt * 4 + r);
            }
        if (p == 0) mbits0 = mb; else if (p == 1) mbits1 = mb; else mbits2 = mb;
    }
    const int d = c * 16 + lr;
    const int wBase = (c >> 1) * 512 + ((c & 1) * 2 + (lr >> 3)) * 128 + lk * 32 + (lr & 7);
    f32x4 ce[4];
    #pragma unroll
    for (int mt = 0; mt < 4; ++mt) ce[mt] = (f32x4)0.0f;

    __syncthreads();

    const f16* HVl = HV + l * 8;   // lane-linear bases: all reads are base + offset
    const f16* HEl = HE + l * 8;
    const size_t cvBase = (size_t)blockIdx.x * 12 * 512 + tid;   // float4 units

    #pragma unroll 1
    for (int it = 0; it < ITERS_; ++it) {
        #pragma unroll 1
        for (int ph = 0; ph < 4; ++ph) {
            // ---- phase-uniform selects
            const int  nkk = (ph == 0) ? 16 : 8;
            const int  ksp = (ph == 0) ? 12 : 4;
            const f16* pa  = (ph == 0) ? HVl : HEl;
            const int  sa  = (ph == 0) ? 12 : 4;
            const f16* pb  = (ph == 0) ? HEl : HVl;
            const int  sb  = (ph == 0) ? 4 : 12;
            const int  ob  = (ph == 0) ? 0 : (ph - 1) * 4;
            const f16* Wp  = (ph == 0) ? WvF : (WeF + (size_t)(ph - 1) * 131072);
            const float* bp = (ph == 0) ? bv : (be + (ph - 1) * 512);
            const unsigned mb = (ph == 0) ? 0xFFFFu
                              : ((ph == 1) ? mbits0 : ((ph == 2) ? mbits1 : mbits2));
            f16* wdst = (ph == 0) ? HE : HV;
            const int wstr = (ph == 0) ? 2048 : 6144;
            const int woff = (ph == 0) ? 0 : (ph - 1) * 2048;

            // ---- GEMM with bias pre-loaded into accumulators
            f32x4 acc[4][4];
            #pragma unroll
            for (int g = 0; g < 4; ++g) {
                const float bg = bp[g * 128 + d];
                #pragma unroll
                for (int mt = 0; mt < 4; ++mt) acc[mt][g] = (f32x4)bg;
            }
            #pragma unroll 1
            for (int kk = 0; kk < nkk; ++kk) {
                const bool lo = kk < ksp;
                f16x8 Ah[4];
                #pragma unroll
                for (int mt = 0; mt < 4; ++mt) {
                    const f16* src = lo ? pa : pb;
                    const int fi = lo ? (mt * sa + kk) : (mt * sb + ob + (kk - ksp));
                    Ah[mt] = *(const f16x8*)(src + fi * 512);
                }
                #pragma unroll
                for (int g = 0; g < 4; ++g) {
                    f16x8 B = *(const f16x8*)(Wp + (size_t)((g * 8 + c) * nkk + kk) * 512 + l * 8);
                    #pragma unroll
                    for (int mt = 0; mt < 4; ++mt)
                        acc[mt][g] = MFh(Ah[mt], B, acc[mt][g]);
                }
            }
            __syncthreads();   // WAR: all reads of this phase's write-tiles complete

            // ---- LSTM cell (unified): state from ce (ph0) or cvG4 (ph>0)
            #pragma unroll
            for (int mt = 0; mt < 4; ++mt) {
                const size_t ci = cvBase + (size_t)(((ph - 1) * 4 + mt)) * 512;
                float cvv[4];
                if (ph == 0) {
                    #pragma unroll
                    for (int r = 0; r < 4; ++r) cvv[r] = ce[mt][r];
                } else if (it > 0) {
                    float4 t = cvG4[ci];
                    cvv[0] = t.x; cvv[1] = t.y; cvv[2] = t.z; cvv[3] = t.w;
                } else {
                    cvv[0] = cvv[1] = cvv[2] = cvv[3] = 0.0f;
                }
                #pragma unroll
                for (int r = 0; r < 4; ++r) {
                    if ((mb >> (mt * 4 + r)) & 1u) {
                        float gi = sigmoid_f(acc[mt][0][r]);
                        float gf = sigmoid_f(acc[mt][1][r]);
                        float gg = tanh_f(acc[mt][2][r]);
                        float go = sigmoid_f(acc[mt][3][r]);
                        float cn = gf * cvv[r] + gi * gg;
                        cvv[r] = cn;
                        wdst[wBase + mt * wstr + woff + r * 8] = (f16)(go * tanh_f(cn));
                    }
                }
                if (ph == 0) {
                    #pragma unroll
                    for (int r = 0; r < 4; ++r) ce[mt][r] = cvv[r];
                } else {
                    cvG4[ci] = make_float4(cvv[0], cvv[1], cvv[2], cvv[3]);
                }
            }
            if (ph == 0 || ph == 3) __syncthreads();   // RAW: HE ready / iter end
        }
    }

    // ---- write final h_v (fp16) for the projection kernel: [vertex][128] row-major
    for (int i = tid; i < 64 * 48; i += 512) {
        const int row = i / 48, seg = i % 48;
        *(f16x8*)&hvOut[(size_t)(e0 + row) * 384 + seg * 8] =
            *(const f16x8*)&HV[((row >> 4) * 12 + (seg >> 2)) * 512 + (seg & 3) * 128 + (row & 15) * 8];
    }
}

// logits = h_v @ out_w^T + out_b, swapped MFMA operands (A=out_w, B=h_v) -> each lane
// holds 4 consecutive vocab cols for one vertex -> float4 stores.
// Single fp16 W term. 768 blocks x 256 thr -> full 98304-vertex coverage.
// 48 KB LDS anchor -> 3 blocks/CU model -> VGPR budget ~170. W register dbuf.
__global__ __launch_bounds__(256) void proj_kernel(
    const f16* __restrict__ hv, const f16* __restrict__ WF,
    const float* __restrict__ out_b, float* __restrict__ out)
{
    __shared__ char occ_pad[49152];
    const int tid = threadIdx.x, l = tid & 63;
    occ_pad[tid] = (char)tid;
    __syncthreads();
    {
        int keep = (int)occ_pad[(tid + 1) & 255];
        asm volatile("" :: "v"(keep));   // occupancy anchor stays live
    }

    const int wid = blockIdx.x * 4 + (tid >> 6);   // 0..3071
    const int v0 = wid * 32;
    const int lr = l & 15, lk = l >> 4;

    f16x8 Bv[2][4];
    #pragma unroll
    for (int vt = 0; vt < 2; ++vt)
        #pragma unroll
        for (int kk = 0; kk < 4; ++kk)
            Bv[vt][kk] = *(const f16x8*)(hv + (v0 + vt * 16 + lr) * D_ + kk * 32 + lk * 8);

    f16x8 Wc[4];
    #pragma unroll
    for (int kk = 0; kk < 4; ++kk)
        Wc[kk] = *(const f16x8*)(WF + (kk * 64 + l) * 8);

    #pragma unroll 2
    for (int nt = 0; nt < 125; ++nt) {
        f16x8 Wn[4];
        if (nt < 124) {
            #pragma unroll
            for (int kk = 0; kk < 4; ++kk)
                Wn[kk] = *(const f16x8*)(WF + (((nt + 1) * 4 + kk) * 64 + l) * 8);
        }
        f32x4 a0 = (f32x4)0.0f, a1 = (f32x4)0.0f;
        #pragma unroll
        for (int kk = 0; kk < 4; ++kk) {
            a0 = MFh(Wc[kk], Bv[0][kk], a0);
            a1 = MFh(Wc[kk], Bv[1][kk], a1);
        }
        const int n0 = nt * 16 + lk * 4;
        const float4 bb = *(const float4*)&out_b[n0];
        {
            const size_t v = (size_t)(v0 + lr);
            float4 o = make_float4(a0[0] + bb.x, a0[1] + bb.y, a0[2] + bb.z, a0[3] + bb.w);
            *(float4*)&out[v * VOCAB_ + n0] = o;
        }
        {
            const size_t v = (size_t)(v0 + 16 + lr);
            float4 o = make_float4(a1[0] + bb.x, a1[1] + bb.y, a1[2] + bb.z, a1[3] + bb.w);
            *(float4*)&out[v * VOCAB_ + n0] = o;
        }
        #pragma unroll
        for (int q = 0; q < 4; ++q) Wc[q] = Wn[q];
    }
}

extern "C" void kernel_launch(void* const* d_in, const int* in_sizes, int n_in,
                              void* d_out, int out_size, void* d_ws, size_t ws_size,
                              hipStream_t stream)
{
    const int*   x_v     = (const int*)  d_in[0];
    const void*  mask    = d_in[1];
    const float* emb     = (const float*)d_in[2];
    const float* eiw     = (const float*)d_in[3];
    const float* eib     = (const float*)d_in[4];
    const float* Wih_v2e = (const float*)d_in[5];
    const float* Whh_v2e = (const float*)d_in[6];
    const float* bih_v2e = (const float*)d_in[7];
    const float* bhh_v2e = (const float*)d_in[8];
    const float* Wih_e2v = (const float*)d_in[9];
    const float* Whh_e2v = (const float*)d_in[10];
    const float* bih_e2v = (const float*)d_in[11];
    const float* bhh_e2v = (const float*)d_in[12];
    const float* out_w   = (const float*)d_in[13];
    const float* out_b   = (const float*)d_in[14];
    float* out = (float*)d_out;

    // d_ws carve (~77.3 MB)
    char* ws = (char*)d_ws;
    f16*    hv   = (f16*)(ws);                  // 25165824 B
    f16*    WvF  = (f16*)(ws + 25165824);       // 524288
    f16*    WeF  = (f16*)(ws + 25690112);       // 786432
    f16*    OwF  = (f16*)(ws + 26476544);       // 512000
    float*  bv   = (float*)(ws + 26988544);     // 2048
    float*  be   = (float*)(ws + 26990592);     // 6144
    int*    flag = (int*)(ws + 26996736);       // 4
    float4* cvG4 = (float4*)(ws + 27000832);    // 50331648  [blk][p][mt][tid] float4

    hipMemsetAsync(flag, 0, 4, stream);
    detect_mask_kernel<<<16, 256, 0, stream>>>((const unsigned int*)mask, flag);
    prep_kernel<<<3568, 256, 0, stream>>>(Wih_v2e, Whh_v2e, bih_v2e, bhh_v2e,
                                          Wih_e2v, Whh_e2v, bih_e2v, bhh_e2v, out_w,
                                          WvF, WeF, OwF, bv, be);
    fused_kernel<<<E_CNT / 64, 512, 0, stream>>>(x_v, emb, eiw, eib,
                                                 WvF, WeF, bv, be,
                                                 mask, flag, cvG4, hv);
    proj_kernel<<<V_CNT / 128, 256, 0, stream>>>(hv, OwF, out_b, out);
}

// Round 19
// 735.647 us; speedup vs baseline: 1.3939x; 1.0921x over previous
//
#include <hip/hip_runtime.h>

#define E_CNT 32768
#define V_CNT 98304
#define D_ 128
#define VOCAB_ 2000
#define ITERS_ 6

typedef unsigned short u16;
typedef _Float16 f16;
typedef __attribute__((ext_vector_type(8))) _Float16 f16x8;
typedef __attribute__((ext_vector_type(4))) float f32x4;

__device__ __forceinline__ f32x4 MFh(f16x8 a, f16x8 b, f32x4 c) {
    return __builtin_amdgcn_mfma_f32_16x16x32_f16(a, b, c, 0, 0, 0);
}
__device__ __forceinline__ float sigmoid_f(float x) {
    return __builtin_amdgcn_rcpf(1.0f + __expf(-x));
}
__device__ __forceinline__ float tanh_f(float x) {
    return fmaf(2.0f, __builtin_amdgcn_rcpf(1.0f + __expf(-2.0f * x)), -1.0f);
}

__global__ void detect_mask_kernel(const unsigned int* __restrict__ m, int* __restrict__ flag) {
    int i = blockIdx.x * 256 + threadIdx.x;
    if (i < 4096 && m[i] > 1u) atomicOr(flag, 1);
}

// Pack weights into MFMA fragment order.
// WvF (fp16): [nt(32)][kk(16)][lane(64)][8]  j = nt*16+(l&15), k = kk*32+(l>>4)*8+r
// WeF (fp16): [p(3)][nt(32)][kk(8)][64][8]
// OwF (fp16, single term): [nt(125)][kk(4)][64][8]
__global__ void prep_kernel(
    const float* __restrict__ Wih_v2e, const float* __restrict__ Whh_v2e,
    const float* __restrict__ bih_v2e, const float* __restrict__ bhh_v2e,
    const float* __restrict__ Wih_e2v, const float* __restrict__ Whh_e2v,
    const float* __restrict__ bih_e2v, const float* __restrict__ bhh_e2v,
    const float* __restrict__ out_w,
    f16* __restrict__ WvF, f16* __restrict__ WeF, f16* __restrict__ OwF,
    float* __restrict__ bv, float* __restrict__ be)
{
    int idx = blockIdx.x * 256 + threadIdx.x;
    if (idx < 262144) {
        const int r = idx & 7, l = (idx >> 3) & 63, t = idx >> 9;
        const int kk = t & 15, nt = t >> 4;
        const int j = nt * 16 + (l & 15);
        const int k = kk * 32 + (l >> 4) * 8 + r;
        const float w = (k < 384) ? Wih_v2e[j * 384 + k] : Whh_v2e[j * 128 + (k - 384)];
        WvF[idx] = (f16)w;
        return;
    }
    idx -= 262144;
    if (idx < 393216) {
        const int r = idx & 7, l = (idx >> 3) & 63, t = idx >> 9;  // t < 768
        const int kk = t & 7, nt = (t >> 3) & 31, p = t >> 8;
        const int j = nt * 16 + (l & 15);
        const int k = kk * 32 + (l >> 4) * 8 + r;
        const float w = (k < 128) ? Wih_e2v[(p * 512 + j) * 128 + k]
                                  : Whh_e2v[(p * 512 + j) * 128 + (k - 128)];
        WeF[idx] = (f16)w;
        return;
    }
    idx -= 393216;
    if (idx < 256000) {
        const int r = idx & 7, l = (idx >> 3) & 63, t = idx >> 9;  // t < 500
        const int kk = t & 3, nt = t >> 2;
        const int j = nt * 16 + (l & 15);
        const int k = kk * 32 + (l >> 4) * 8 + r;
        OwF[idx] = (f16)out_w[j * 128 + k];
        return;
    }
    idx -= 256000;
    if (idx < 512) { bv[idx] = bih_v2e[idx] + bhh_v2e[idx]; return; }
    idx -= 512;
    if (idx < 1536) { be[idx] = bih_e2v[idx] + bhh_e2v[idx]; return; }
}

// Persistent iteration kernel: 512 thr / 8 waves / 32 EDGES / all 6 iterations.
// r19: SMALL BLOCKS FOR CO-RESIDENCY. r15-r18 invariance (~525us across 2x occupancy,
// spills, barriers, code size) - common factor was 1 block/CU: every barrier drained
// the whole CU, B-load latency exposed with 2 waves/SIMD. Now: LDS = HV 24K + HE 8K +
// 8.5K pad = 41.4 KB, sized so LDS-max = 3 blocks/CU (>40KB excludes 4) -> allocator
// targets 24 waves/CU = 6/EU = 85-VGPR budget >= live set ~65 (mt=2: acc 32 + A 8 +
// B 4 + ce 8 + misc) -> no spills (r17 trap: a 4-block/64-VGPR target would spill).
// 3 blocks x 8 waves = 24 waves/CU: barriers stall 1/3 of the CU, 6 waves/SIMD hide
// B-load latency. Compact unified phase loop (r18), coalesced cvG4 (r15).
__global__ __launch_bounds__(512)
void fused_kernel(
    const int* __restrict__ x_v,
    const float* __restrict__ emb,
    const float* __restrict__ eiw, const float* __restrict__ eib,
    const f16* __restrict__ WvF, const f16* __restrict__ WeF,
    const float* __restrict__ bv, const float* __restrict__ be,
    const void* __restrict__ mask, const int* __restrict__ flagp,
    float4* __restrict__ cvG4,
    f16* __restrict__ hvOut)
{
    __shared__ f16 HV[12288];    // 24 KB, fragment order [mt(2)*12+kk][lane][8]
    __shared__ f16 HE[4096];     //  8 KB, fragment order [mt(2)*4+kk][lane][8]
    __shared__ char PADL[8704];  //  8.5 KB occupancy governor -> 3 blocks/CU max

    const int tid = threadIdx.x;
    const int c = tid >> 6, l = tid & 63;
    const int lr = l & 15, lk = l >> 4;
    const int e0 = blockIdx.x * 32;

    PADL[tid] = (char)tid;       // keep the pad allocated

    // ---- init h_v from embeddings (fp16x8 chunks into fragment slots)
    for (int i = tid; i < 32 * 48; i += 512) {
        const int row = i / 48, seg = i % 48;
        int id = x_v[(e0 + row) * 3 + (seg >> 4)];
        if (id < 0 || id > VOCAB_) id = VOCAB_;
        const float* s = emb + id * D_ + ((seg * 8) & 127);
        float4 a = *(const float4*)s, b = *(const float4*)(s + 4);
        f16x8 H;
        H[0] = (f16)a.x; H[1] = (f16)a.y; H[2] = (f16)a.z; H[3] = (f16)a.w;
        H[4] = (f16)b.x; H[5] = (f16)b.y; H[6] = (f16)b.z; H[7] = (f16)b.w;
        *(f16x8*)&HV[((row >> 4) * 12 + (seg >> 2)) * 512 + (seg & 3) * 128 + (row & 15) * 8] = H;
    }
    // ---- init h_e (same vector for every edge)
    if (tid < 512) {
        const int i = tid;       // 32*16 = 512 chunks exactly
        const int row = i / 16, seg = i % 16;
        f16x8 H;
        #pragma unroll
        for (int j = 0; j < 8; ++j) H[j] = (f16)(eiw[seg * 8 + j] + eib[seg * 8 + j]);
        *(f16x8*)&HE[((row >> 4) * 4 + (seg >> 2)) * 512 + (seg & 3) * 128 + (row & 15) * 8] = H;
    }

    // ---- per-lane constants
    const int isByte = *flagp;
    unsigned mbits0 = 0, mbits1 = 0, mbits2 = 0;
    #pragma unroll
    for (int p = 0; p < 3; ++p) {
        unsigned mb = 0;
        #pragma unroll
        for (int mt = 0; mt < 2; ++mt)
            #pragma unroll
            for (int r = 0; r < 4; ++r) {
                const int v = (e0 + mt * 16 + lk * 4 + r) * 3 + p;
                const bool m = isByte ? (((const unsigned char*)mask)[v] != 0)
                                      : (((const int*)mask)[v] != 0);
                mb |= (unsigned)m << (mt * 4 + r);
            }
        if (p == 0) mbits0 = mb; else if (p == 1) mbits1 = mb; else mbits2 = mb;
    }
    const int d = c * 16 + lr;
    const int wBase = (c >> 1) * 512 + ((c & 1) * 2 + (lr >> 3)) * 128 + lk * 32 + (lr & 7);
    f32x4 ce[2];
    ce[0] = (f32x4)0.0f; ce[1] = (f32x4)0.0f;

    __syncthreads();
    {
        int keep = (int)PADL[(tid + 1) & 511];
        asm volatile("" :: "v"(keep));
    }

    const f16* HVl = HV + l * 8;
    const f16* HEl = HE + l * 8;
    const size_t cvBase = (size_t)blockIdx.x * 6 * 512 + tid;   // float4 units

    #pragma unroll 1
    for (int it = 0; it < ITERS_; ++it) {
        #pragma unroll 1
        for (int ph = 0; ph < 4; ++ph) {
            const int  nkk = (ph == 0) ? 16 : 8;
            const int  ksp = (ph == 0) ? 12 : 4;
            const f16* pa  = (ph == 0) ? HVl : HEl;
            const int  sa  = (ph == 0) ? 12 : 4;
            const f16* pb  = (ph == 0) ? HEl : HVl;
            const int  sb  = (ph == 0) ? 4 : 12;
            const int  ob  = (ph == 0) ? 0 : (ph - 1) * 4;
            const f16* Wp  = (ph == 0) ? WvF : (WeF + (size_t)(ph - 1) * 131072);
            const float* bp = (ph == 0) ? bv : (be + (ph - 1) * 512);
            const unsigned mb = (ph == 0) ? 0xFFu
                              : ((ph == 1) ? mbits0 : ((ph == 2) ? mbits1 : mbits2));
            f16* wdst = (ph == 0) ? HE : HV;
            const int wstr = (ph == 0) ? 2048 : 6144;
            const int woff = (ph == 0) ? 0 : (ph - 1) * 2048;

            // ---- GEMM with bias pre-loaded into accumulators
            f32x4 acc[2][4];
            #pragma unroll
            for (int g = 0; g < 4; ++g) {
                const float bg = bp[g * 128 + d];
                acc[0][g] = (f32x4)bg;
                acc[1][g] = (f32x4)bg;
            }
            #pragma unroll 1
            for (int kk = 0; kk < nkk; ++kk) {
                const bool lo = kk < ksp;
                f16x8 Ah[2];
                #pragma unroll
                for (int mt = 0; mt < 2; ++mt) {
                    const f16* src = lo ? pa : pb;
                    const int fi = lo ? (mt * sa + kk) : (mt * sb + ob + (kk - ksp));
                    Ah[mt] = *(const f16x8*)(src + fi * 512);
                }
                #pragma unroll
                for (int g = 0; g < 4; ++g) {
                    f16x8 B = *(const f16x8*)(Wp + (size_t)((g * 8 + c) * nkk + kk) * 512 + l * 8);
                    acc[0][g] = MFh(Ah[0], B, acc[0][g]);
                    acc[1][g] = MFh(Ah[1], B, acc[1][g]);
                }
            }
            __syncthreads();   // WAR: all reads of this phase's write-tiles complete

            // ---- LSTM cell: state from ce (ph0) or cvG4 (ph>0)
            #pragma unroll
            for (int mt = 0; mt < 2; ++mt) {
                const size_t ci = cvBase + (size_t)((ph - 1) * 2 + mt) * 512;
                float cvv[4];
                if (ph == 0) {
                    #pragma unroll
                    for (int r = 0; r < 4; ++r) cvv[r] = ce[mt][r];
                } else if (it > 0) {
                    float4 t = cvG4[ci];
                    cvv[0] = t.x; cvv[1] = t.y; cvv[2] = t.z; cvv[3] = t.w;
                } else {
                    cvv[0] = cvv[1] = cvv[2] = cvv[3] = 0.0f;
                }
                #pragma unroll
                for (int r = 0; r < 4; ++r) {
                    if ((mb >> (mt * 4 + r)) & 1u) {
                        float gi = sigmoid_f(acc[mt][0][r]);
                        float gf = sigmoid_f(acc[mt][1][r]);
                        float gg = tanh_f(acc[mt][2][r]);
                        float go = sigmoid_f(acc[mt][3][r]);
                        float cn = gf * cvv[r] + gi * gg;
                        cvv[r] = cn;
                        wdst[wBase + mt * wstr + woff + r * 8] = (f16)(go * tanh_f(cn));
                    }
                }
                if (ph == 0) {
                    #pragma unroll
                    for (int r = 0; r < 4; ++r) ce[mt][r] = cvv[r];
                } else {
                    cvG4[ci] = make_float4(cvv[0], cvv[1], cvv[2], cvv[3]);
                }
            }
            if (ph == 0 || ph == 3) __syncthreads();   // RAW: HE ready / iter end
        }
    }

    // ---- write final h_v (fp16) for the projection kernel: [vertex][128] row-major
    for (int i = tid; i < 32 * 48; i += 512) {
        const int row = i / 48, seg = i % 48;
        *(f16x8*)&hvOut[(size_t)(e0 + row) * 384 + seg * 8] =
            *(const f16x8*)&HV[((row >> 4) * 12 + (seg >> 2)) * 512 + (seg & 3) * 128 + (row & 15) * 8];
    }
}

// logits = h_v @ out_w^T + out_b, swapped MFMA operands (A=out_w, B=h_v) -> each lane
// holds 4 consecutive vocab cols for one vertex -> float4 stores.
// Single fp16 W term. 768 blocks x 256 thr -> full 98304-vertex coverage.
// 48 KB LDS anchor -> 3 blocks/CU model -> VGPR budget ~170. W register dbuf.
__global__ __launch_bounds__(256) void proj_kernel(
    const f16* __restrict__ hv, const f16* __restrict__ WF,
    const float* __restrict__ out_b, float* __restrict__ out)
{
    __shared__ char occ_pad[49152];
    const int tid = threadIdx.x, l = tid & 63;
    occ_pad[tid] = (char)tid;
    __syncthreads();
    {
        int keep = (int)occ_pad[(tid + 1) & 255];
        asm volatile("" :: "v"(keep));
    }

    const int wid = blockIdx.x * 4 + (tid >> 6);   // 0..3071
    const int v0 = wid * 32;
    const int lr = l & 15, lk = l >> 4;

    f16x8 Bv[2][4];
    #pragma unroll
    for (int vt = 0; vt < 2; ++vt)
        #pragma unroll
        for (int kk = 0; kk < 4; ++kk)
            Bv[vt][kk] = *(const f16x8*)(hv + (v0 + vt * 16 + lr) * D_ + kk * 32 + lk * 8);

    f16x8 Wc[4];
    #pragma unroll
    for (int kk = 0; kk < 4; ++kk)
        Wc[kk] = *(const f16x8*)(WF + (kk * 64 + l) * 8);

    #pragma unroll 2
    for (int nt = 0; nt < 125; ++nt) {
        f16x8 Wn[4];
        if (nt < 124) {
            #pragma unroll
            for (int kk = 0; kk < 4; ++kk)
                Wn[kk] = *(const f16x8*)(WF + (((nt + 1) * 4 + kk) * 64 + l) * 8);
        }
        f32x4 a0 = (f32x4)0.0f, a1 = (f32x4)0.0f;
        #pragma unroll
        for (int kk = 0; kk < 4; ++kk) {
            a0 = MFh(Wc[kk], Bv[0][kk], a0);
            a1 = MFh(Wc[kk], Bv[1][kk], a1);
        }
        const int n0 = nt * 16 + lk * 4;
        const float4 bb = *(const float4*)&out_b[n0];
        {
            const size_t v = (size_t)(v0 + lr);
            float4 o = make_float4(a0[0] + bb.x, a0[1] + bb.y, a0[2] + bb.z, a0[3] + bb.w);
            *(float4*)&out[v * VOCAB_ + n0] = o;
        }
        {
            const size_t v = (size_t)(v0 + 16 + lr);
            float4 o = make_float4(a1[0] + bb.x, a1[1] + bb.y, a1[2] + bb.z, a1[3] + bb.w);
            *(float4*)&out[v * VOCAB_ + n0] = o;
        }
        #pragma unroll
        for (int q = 0; q < 4; ++q) Wc[q] = Wn[q];
    }
}

extern "C" void kernel_launch(void* const* d_in, const int* in_sizes, int n_in,
                              void* d_out, int out_size, void* d_ws, size_t ws_size,
                              hipStream_t stream)
{
    const int*   x_v     = (const int*)  d_in[0];
    const void*  mask    = d_in[1];
    const float* emb     = (const float*)d_in[2];
    const float* eiw     = (const float*)d_in[3];
    const float* eib     = (const float*)d_in[4];
    const float* Wih_v2e = (const float*)d_in[5];
    const float* Whh_v2e = (const float*)d_in[6];
    const float* bih_v2e = (const float*)d_in[7];
    const float* bhh_v2e = (const float*)d_in[8];
    const float* Wih_e2v = (const float*)d_in[9];
    const float* Whh_e2v = (const float*)d_in[10];
    const float* bih_e2v = (const float*)d_in[11];
    const float* bhh_e2v = (const float*)d_in[12];
    const float* out_w   = (const float*)d_in[13];
    const float* out_b   = (const float*)d_in[14];
    float* out = (float*)d_out;

    // d_ws carve (~77.3 MB)
    char* ws = (char*)d_ws;
    f16*    hv   = (f16*)(ws);                  // 25165824 B
    f16*    WvF  = (f16*)(ws + 25165824);       // 524288
    f16*    WeF  = (f16*)(ws + 25690112);       // 786432
    f16*    OwF  = (f16*)(ws + 26476544);       // 512000
    float*  bv   = (float*)(ws + 26988544);     // 2048
    float*  be   = (float*)(ws + 26990592);     // 6144
    int*    flag = (int*)(ws + 26996736);       // 4
    float4* cvG4 = (float4*)(ws + 27000832);    // 50331648  [blk][(p*2+mt)][tid] float4

    hipMemsetAsync(flag, 0, 4, stream);
    detect_mask_kernel<<<16, 256, 0, stream>>>((const unsigned int*)mask, flag);
    prep_kernel<<<3568, 256, 0, stream>>>(Wih_v2e, Whh_v2e, bih_v2e, bhh_v2e,
                                          Wih_e2v, Whh_e2v, bih_e2v, bhh_e2v, out_w,
                                          WvF, WeF, OwF, bv, be);
    fused_kernel<<<E_CNT / 32, 512, 0, stream>>>(x_v, emb, eiw, eib,
                                                 WvF, WeF, bv, be,
                                                 mask, flag, cvG4, hv);
    proj_kernel<<<V_CNT / 128, 256, 0, stream>>>(hv, OwF, out_b, out);
}